// Round 11
// baseline (361.575 us; speedup 1.0000x reference)
//
#include <hip/hip_runtime.h>
#include <hip/hip_bf16.h>

#define N_ATOMS 100000
#define K_NBR   64
#define N_STRUCT 32
#define HID     128
#define N_EDGE  (N_ATOMS * K_NBR)       // 6,400,000
#define ATOMS_PB 32                     // atoms per edge block
#define EDGES_PB (ATOMS_PB * K_NBR)     // 2048
#define NBLK_EL (N_ATOMS / ATOMS_PB)    // 3125 (exact)
#define NBLK_A  (N_ATOMS / 32)          // 3125 (32 atoms per force block)

typedef unsigned int uint;
typedef unsigned long long ull;
typedef _Float16 h2 __attribute__((ext_vector_type(2)));
typedef __fp16  p2 __attribute__((ext_vector_type(2)));   // cvt_pkrtz result type
typedef float   f2 __attribute__((ext_vector_type(2)));   // packed dual-f32 (v_pk_*)

#if __has_builtin(__builtin_amdgcn_exp2f)
#define EXP2(v) __builtin_amdgcn_exp2f(v)
#else
#define EXP2(v) __expf((v) * 0.69314718056f)
#endif

#if __has_builtin(__builtin_amdgcn_fdot2)
#define FDOT2(a, b, c) __builtin_amdgcn_fdot2((a), (b), (c), false)
#else
__device__ __forceinline__ float FDOT2(h2 a, h2 b, float c) {
    return fmaf((float)a.y, (float)b.y, fmaf((float)a.x, (float)b.x, c));
}
#endif

#define PKFMA(a, b, c) __builtin_elementwise_fma((a), (b), (c))
#define SWAP2(v) __builtin_shufflevector((v), (v), 1, 0)

union hcast { p2 p; h2 h; uint u; };

__device__ __forceinline__ h2 pkh(float a, float b) {     // f32 pair -> f16x2 (RTZ)
    hcast c; c.p = __builtin_amdgcn_cvt_pkrtz(a, b); return c.h;
}
__device__ __forceinline__ uint pku(float a, float b) {   // f32 pair -> packed u32
    hcast c; c.p = __builtin_amdgcn_cvt_pkrtz(a, b); return c.u;
}
__device__ __forceinline__ h2 u2h(uint u) {
    hcast c; c.u = u; return c.h;
}

__device__ __forceinline__ uint bf_rne(float f) {        // fp32 -> bf16 bits (RNE)
    uint u = __float_as_uint(f);
    return (u + 0x7fffu + ((u >> 16) & 1u)) >> 16;
}
__device__ __forceinline__ float ubf_lo(uint u) { return __uint_as_float(u << 16); }
__device__ __forceinline__ float ubf_hi(uint u) { return __uint_as_float(u & 0xffff0000u); }

// 16-lane (DPP row) sum; result lands in lane 15 of each 16-lane row.
__device__ __forceinline__ float red16(float x) {
    union { float f; int i; } a, b;
    a.f = x;
    b.i = __builtin_amdgcn_update_dpp(0, a.i, 0x118, 0xf, 0xf, false); a.f += b.f; // row_shr:8
    b.i = __builtin_amdgcn_update_dpp(0, a.i, 0x114, 0xf, 0xf, false); a.f += b.f; // row_shr:4
    b.i = __builtin_amdgcn_update_dpp(0, a.i, 0x112, 0xf, 0xf, false); a.f += b.f; // row_shr:2
    b.i = __builtin_amdgcn_update_dpp(0, a.i, 0x111, 0xf, 0xf, false); a.f += b.f; // row_shr:1
    return a.f;
}

// ---------------------------------------------------------------------------
// Weight prep (1 block). Pair-packed layouts for the f2 (v_pk_f32) d-loop:
//   pwa4[j] = {wx[2j],wx[2j+1], wy[2j],wy[2j+1]}   (wx/wy/wz scaled by 2log2e)
//   pwb4[j] = {wz[2j],wz[2j+1], wv[2j],wv[2j+1]}   (wv = w2, unscaled)
//   gh4[2g],gh4[2g+1] = f16-packed {4*w2*W1[c,d]} for d-group g.
// identities: ex = e^{2p} = exp2(x·pw); r = 1/(1+ex); t = 1-2r;
//             e = sumw2 - 2 sum w2 r; (1-t^2)/4 = r - r^2.
// ---------------------------------------------------------------------------
__global__ void prep_kernel(const float* __restrict__ W1, const float* __restrict__ w2,
                            float4* __restrict__ pwa4, float4* __restrict__ pwb4,
                            uint4* __restrict__ gh4, float* __restrict__ sumw2)
{
    __shared__ float spx[HID], spy[HID], spz[HID], spv[HID];
    __shared__ float sgx[HID], sgy[HID], sgz[HID];
    __shared__ float sw_[2];
    const float L2E2 = 2.885390082f;     // 2*log2(e)
    int d = threadIdx.x;                 // 128 threads
    float w0 = W1[d], w1 = W1[HID + d], wc = W1[2 * HID + d], wv = w2[d];
    spx[d] = L2E2 * w0; spy[d] = L2E2 * w1; spz[d] = L2E2 * wc; spv[d] = wv;
    sgx[d] = 4.f * wv * w0; sgy[d] = 4.f * wv * w1; sgz[d] = 4.f * wv * wc;
    float v = wv;
    for (int off = 32; off; off >>= 1) v += __shfl_down(v, off, 64);
    if ((d & 63) == 0) sw_[d >> 6] = v;
    __syncthreads();
    if (d == 0) sumw2[0] = sw_[0] + sw_[1];
    if (d < HID / 2) {
        int b = 2 * d;
        pwa4[d] = make_float4(spx[b], spx[b + 1], spy[b], spy[b + 1]);
        pwb4[d] = make_float4(spz[b], spz[b + 1], spv[b], spv[b + 1]);
    }
    if (d < HID / 4) {
        int b = 4 * d;
        uint c0 = pku(sgx[b],     sgx[b + 1]);
        uint c1 = pku(sgx[b + 2], sgx[b + 3]);
        uint c2 = pku(sgy[b],     sgy[b + 1]);
        uint c3 = pku(sgy[b + 2], sgy[b + 3]);
        uint c4 = pku(sgz[b],     sgz[b + 1]);
        uint c5 = pku(sgz[b + 2], sgz[b + 3]);
        gh4[2 * d]     = make_uint4(c0, c1, c2, c3);
        gh4[2 * d + 1] = make_uint4(c4, c5, 0u, 0u);
    }
}

// ---------------------------------------------------------------------------
// Edge MLP with block-local compaction: block owns 32 atoms (2048 edges).
// Phase A compacts unmasked local ids into LDS and stores the per-64-edge
// unmask BITMAP (no gr8 zero-fill — all gr8 reads downstream are bm-gated).
// Phase B: dense d-loop, R11 structure EXACTLY (known-best).
// Phase C (R14): per-edge bf16 grads stashed in LDS; block reduces its own
// 32 atoms' FIRST-term sums and writes first[n]. FROZEN at R14 config.
// ---------------------------------------------------------------------------
__global__ __launch_bounds__(256) void edge_local(
    const float* __restrict__ x, const int* __restrict__ mask,
    const int* __restrict__ batch,
    const float4* __restrict__ pwa4, const float4* __restrict__ pwb4,
    const uint4* __restrict__ gh4,
    const float* __restrict__ sumw2p,
    uint2* __restrict__ gr8, ull* __restrict__ bm, float* __restrict__ part,
    float* __restrict__ first)
{
    __shared__ unsigned short list[EDGES_PB];
    __shared__ uint sgL[EDGES_PB];       // per-edge grad lo word (bf16 g0|g1)
    __shared__ uint sgH[EDGES_PB];       // per-edge grad hi word (bf16 g2)
    __shared__ int   lcnt;
    __shared__ float sp[N_STRUCT];
    __shared__ int   sbatch[ATOMS_PB];

    const int tid = threadIdx.x, lane = tid & 63;
    const int ebase = blockIdx.x * EDGES_PB;

    if (tid == 0) lcnt = 0;
    if (tid < N_STRUCT) sp[tid] = 0.f;
    if (tid < ATOMS_PB) sbatch[tid] = batch[blockIdx.x * ATOMS_PB + tid];
    __syncthreads();

    #pragma unroll
    for (int p = 0; p < EDGES_PB / 256; ++p) {           // 8 passes, coalesced
        int le = p * 256 + tid;
        int m = mask[ebase + le];
        unsigned long long bal = __ballot(m == 0);
        int wcnt = __popcll(bal);
        int pre  = __popcll(bal & ((1ull << lane) - 1ull));
        int wbase;
        if (lane == 0) {
            wbase = atomicAdd(&lcnt, wcnt);              // block-local ticket
            bm[(ebase + le) >> 6] = bal;                 // unmask bitmap word
        }
        wbase = __shfl(wbase, 0, 64);
        if (m == 0) list[wbase + pre] = (unsigned short)le;
        else        { sgL[le] = 0u; sgH[le] = 0u; }      // masked grad == 0 (LDS only)
    }
    __syncthreads();

    const int L = lcnt;
    const float sumw2 = sumw2p[0];

    for (int i = tid; i < L; i += 256) {
        int le  = list[i];
        int eid = ebase + le;
        const float* xp = x + (size_t)eid * 3;
        float x0 = xp[0], x1 = xp[1], x2 = xp[2];
        const f2 x0v = {x0, x0}, x1v = {x1, x1}, x2v = {x2, x2};
        const f2 onev = {1.f, 1.f};
        f2 rs = {0.f, 0.f};
        float g0 = 0.f, g1 = 0.f, g2 = 0.f;
        for (int j = 0; j < HID / 2; j += 2) {           // 2 dim-pairs = 4 dims
            float4 Aa = pwa4[j],     Ab = pwb4[j];
            float4 Ba = pwa4[j + 1], Bb = pwb4[j + 1];
            uint4 GA = gh4[j];
            uint4 GB = gh4[j + 1];
            f2 wx01 = {Aa.x, Aa.y}, wy01 = {Aa.z, Aa.w};
            f2 wz01 = {Ab.x, Ab.y}, wv01 = {Ab.z, Ab.w};
            f2 wx23 = {Ba.x, Ba.y}, wy23 = {Ba.z, Ba.w};
            f2 wz23 = {Bb.x, Bb.y}, wv23 = {Bb.z, Bb.w};
            f2 p01 = PKFMA(x0v, wx01, PKFMA(x1v, wy01, x2v * wz01));
            f2 p23 = PKFMA(x0v, wx23, PKFMA(x1v, wy23, x2v * wz23));
            f2 e01 = {EXP2(p01.x), EXP2(p01.y)};
            f2 e23 = {EXP2(p23.x), EXP2(p23.y)};
            f2 a01 = e01 + onev, a23 = e23 + onev;
            float pab = a01.x * a01.y, pcd = a23.x * a23.y;
            float q   = __builtin_amdgcn_rcpf(pab * pcd); // one rcp per 4 d
            float qab = q * pcd, qcd = q * pab;
            f2 r01 = (f2){qab, qab} * SWAP2(a01);         // {qab*ab, qab*aa}
            f2 r23 = (f2){qcd, qcd} * SWAP2(a23);
            rs = PKFMA(wv01, r01, rs);
            rs = PKFMA(wv23, r23, rs);
            f2 s01 = PKFMA(-r01, r01, r01);               // r-r^2 = (1-t^2)/4
            f2 s23 = PKFMA(-r23, r23, r23);
            h2 sab = pkh(s01.x, s01.y);
            h2 scd = pkh(s23.x, s23.y);
            g0 = FDOT2(sab, u2h(GA.x), g0);
            g0 = FDOT2(scd, u2h(GA.y), g0);
            g1 = FDOT2(sab, u2h(GA.z), g1);
            g1 = FDOT2(scd, u2h(GA.w), g1);
            g2 = FDOT2(sab, u2h(GB.x), g2);
            g2 = FDOT2(scd, u2h(GB.y), g2);
        }
        float e = fmaf(-2.f, rs.x + rs.y, sumw2);
        uint lo = bf_rne(g0) | (bf_rne(g1) << 16);
        uint hi = bf_rne(g2);
        gr8[eid] = make_uint2(lo, hi);
        sgL[le] = lo; sgH[le] = hi;                       // LDS stash for phase C
        atomicAdd(&sp[sbatch[le >> 6]], e);
    }
    __syncthreads();
    if (tid < N_STRUCT) part[(size_t)tid * NBLK_EL + blockIdx.x] = sp[tid];

    // phase C: FIRST-term per-atom sums. 16 threads/atom, 2 passes.
    #pragma unroll
    for (int pass = 0; pass < 2; ++pass) {
        int la = pass * 16 + (tid >> 4);                 // atom 0..31
        int o  = tid & 15;
        float f0 = 0.f, f1 = 0.f, f2_ = 0.f;
        #pragma unroll
        for (int j = 0; j < 4; ++j) {                    // edges k = o*4+j
            int le = la * 64 + o * 4 + j;
            uint lo = sgL[le], hi = sgH[le];
            f0  += ubf_lo(lo);
            f1  += ubf_hi(lo);
            f2_ += ubf_lo(hi);
        }
        f0 = red16(f0); f1 = red16(f1); f2_ = red16(f2_);
        if (o == 15) {
            float* fo = first + (size_t)(blockIdx.x * ATOMS_PB + la) * 3;
            fo[0] = f0; fo[1] = f1; fo[2] = f2_;
        }
    }
}

// ---------------------------------------------------------------------------
// Forces (gather-only). R15 structure (branchless clamped loads, 8 waves/SIMD)
// + R16: the two RANDOM access classes (filter words, gathers) become
// NONTEMPORAL (`nt` flag): they bypass L1 allocation. Theory: atom is capped
// at ~16 outstanding misses/CU (one divergent load saturates the L1 miss
// queue); nt loads take the streaming path and should raise concurrency.
// Gathered data has zero reuse here, so nt is semantically right regardless.
// Blocks 0..31 also reduce preds partials.
// ---------------------------------------------------------------------------
__global__ __launch_bounds__(256, 8) void atom_fused(
    const uint2* __restrict__ gr8, const int* __restrict__ nidx,
    const int* __restrict__ pos,
    const ull* __restrict__ bm, const float* __restrict__ part,
    const float* __restrict__ first,
    float* __restrict__ out)
{
    __shared__ int tile[64][33];
    __shared__ float sv[4];
    const int tid = threadIdx.x, lane = tid & 63, w = tid >> 6;
    const int n0 = blockIdx.x * 32;

    #pragma unroll
    for (int i = 0; i < 8; ++i) {                  // coalesced read of nidx[K,N]
        int k = i * 8 + (tid >> 5), c = tid & 31;
        tile[k][c] = nidx[k * N_ATOMS + n0 + c];
    }
    __syncthreads();

    const int grp = lane >> 4, kk = lane & 15;
    const ull* gr8w = (const ull*)gr8;             // 8B view for nt loads

    #pragma unroll
    for (int s = 0; s < 2; ++s) {                  // wave owns 8 atoms: 2 batches of 4
        int nl = w * 8 + s * 4 + grp;
        int n  = n0 + nl;
        ull bmw = bm[n];                           // wave-uniform-ish unmask word

        // phase 1: dense pos loads + clamped reverse-ids (no branches)
        int  gs[4];
        uint sb[4];
        #pragma unroll
        for (int ks = 0; ks < 4; ++ks) {
            int k  = ks * 16 + kk;
            int ei = n * 64 + k;
            sb[ks] = (uint)((bmw >> k) & 1ull);    // source edge unmasked?
            int p  = pos[ei];                      // unconditional, coalesced
            int gt = tile[k][nl] * 64 + p;
            gs[ks] = sb[ks] ? gt : 0;              // clamp dead lanes to word 0
        }

        // phase 2: 4 unconditional NONTEMPORAL filter-word loads (random 8B)
        ull fw[4];
        #pragma unroll
        for (int ks = 0; ks < 4; ++ks)
            fw[ks] = __builtin_nontemporal_load(&bm[gs[ks] >> 6]);

        // phase 3: 4 unconditional NONTEMPORAL gathers (random 8B)
        uint ok[4];
        int  ga[4];
        #pragma unroll
        for (int ks = 0; ks < 4; ++ks) {
            ok[ks] = sb[ks] & (uint)((fw[ks] >> (gs[ks] & 63)) & 1ull);
            ga[ks] = ok[ks] ? gs[ks] : 0;
        }
        float f0 = 0.f, f1 = 0.f, f2_ = 0.f;
        #pragma unroll
        for (int ks = 0; ks < 4; ++ks) {
            ull B8 = __builtin_nontemporal_load(&gr8w[ga[ks]]);
            uint bx = ok[ks] ? (uint)B8 : 0u;
            uint by = ok[ks] ? (uint)(B8 >> 32) : 0u;
            f0  += ubf_lo(bx);
            f1  += ubf_hi(bx);
            f2_ += ubf_lo(by);
        }

        // phase 4: reduce SECOND term, store first - second
        f0 = red16(f0); f1 = red16(f1); f2_ = red16(f2_);
        if (kk == 15) {
            const float* fi = first + (size_t)n * 3;
            float* fo = out + N_STRUCT + (size_t)n * 3;
            fo[0] = fi[0] - f0; fo[1] = fi[1] - f1; fo[2] = fi[2] - f2_;
        }
    }

    if (blockIdx.x < N_STRUCT) {                   // fused preds reduction
        int s = blockIdx.x;
        float v = 0.f;
        for (int i = tid; i < NBLK_EL; i += 256) v += part[(size_t)s * NBLK_EL + i];
        for (int off = 32; off; off >>= 1) v += __shfl_down(v, off, 64);
        if (lane == 0) sv[w] = v;
        __syncthreads();
        if (tid == 0) out[s] = sv[0] + sv[1] + sv[2] + sv[3];
    }
}

// ---------------------------------------------------------------------------
extern "C" void kernel_launch(void* const* d_in, const int* in_sizes, int n_in,
                              void* d_out, int out_size, void* d_ws, size_t ws_size,
                              hipStream_t stream)
{
    const float* x    = (const float*)d_in[0];
    const int*   nidx = (const int*)d_in[1];   // [K, N]
    const int*   npos = (const int*)d_in[2];   // [N, K]
    const int*   mask = (const int*)d_in[3];   // [N, K]
    const int*   bidx = (const int*)d_in[4];   // [N]
    const float* W1   = (const float*)d_in[5]; // [3, HID]
    const float* w2   = (const float*)d_in[6]; // [HID]
    float* out = (float*)d_out;

    char* ws = (char*)d_ws;
    uint2* gr8  = (uint2*)ws;                                       // 51.2 MB
    ull*   bm   = (ull*)(ws + (size_t)N_EDGE * 8);                  // 800 KB
    float* part = (float*)(ws + (size_t)N_EDGE * 8 + (size_t)(N_EDGE / 64) * 8);
    char*  t1   = ws + (size_t)N_EDGE * 8 + (size_t)(N_EDGE / 64) * 8
                     + (size_t)N_STRUCT * NBLK_EL * sizeof(float);
    float* first = (float*)t1;                                      // 1.2 MB
    char*  tail  = t1 + (size_t)N_ATOMS * 3 * sizeof(float);
    float4* pwa4  = (float4*)tail;                                  // 1 KB
    float4* pwb4  = (float4*)(tail + (HID / 2) * 16);               // 1 KB
    uint4*  gh4   = (uint4*)(tail + 2 * (HID / 2) * 16);            // 1 KB
    float*  sumw2 = (float*)(tail + 3 * (HID / 2) * 16);

    hipLaunchKernelGGL(prep_kernel, dim3(1), dim3(128), 0, stream,
                       W1, w2, pwa4, pwb4, gh4, sumw2);
    hipLaunchKernelGGL(edge_local, dim3(NBLK_EL), dim3(256), 0, stream,
                       x, mask, bidx, pwa4, pwb4, gh4, sumw2, gr8, bm, part, first);
    hipLaunchKernelGGL(atom_fused, dim3(NBLK_A), dim3(256), 0, stream,
                       gr8, nidx, npos, bm, part, first, out);
}

// Round 13
// 317.356 us; speedup vs baseline: 1.1393x; 1.1393x over previous
//
#include <hip/hip_runtime.h>
#include <hip/hip_bf16.h>

#define N_ATOMS 100000
#define K_NBR   64
#define N_STRUCT 32
#define HID     128
#define N_EDGE  (N_ATOMS * K_NBR)       // 6,400,000
#define ATOMS_PB 32                     // atoms per edge block
#define EDGES_PB (ATOMS_PB * K_NBR)     // 2048
#define NBLK_EL (N_ATOMS / ATOMS_PB)    // 3125 (exact)
#define NBLK_A  (N_ATOMS / 32)          // 3125 (32 atoms per force block)

typedef unsigned int uint;
typedef unsigned short ushort;
typedef unsigned long long ull;
typedef float f2 __attribute__((ext_vector_type(2)));     // packed dual-f32 (v_pk_*)

#if __has_builtin(__builtin_amdgcn_exp2f)
#define EXP2(v) __builtin_amdgcn_exp2f(v)
#else
#define EXP2(v) __expf((v) * 0.69314718056f)
#endif

#define PKFMA(a, b, c) __builtin_elementwise_fma((a), (b), (c))
#define SWAP2(v) __builtin_shufflevector((v), (v), 1, 0)

__device__ __forceinline__ uint bf_rne(float f) {        // fp32 -> bf16 bits (RNE)
    uint u = __float_as_uint(f);
    return (u + 0x7fffu + ((u >> 16) & 1u)) >> 16;
}
__device__ __forceinline__ float ubf_lo(uint u) { return __uint_as_float(u << 16); }
__device__ __forceinline__ float ubf_hi(uint u) { return __uint_as_float(u & 0xffff0000u); }

// 16-lane (DPP row) sum; result lands in lane 15 of each 16-lane row.
__device__ __forceinline__ float red16(float x) {
    union { float f; int i; } a, b;
    a.f = x;
    b.i = __builtin_amdgcn_update_dpp(0, a.i, 0x118, 0xf, 0xf, false); a.f += b.f; // row_shr:8
    b.i = __builtin_amdgcn_update_dpp(0, a.i, 0x114, 0xf, 0xf, false); a.f += b.f; // row_shr:4
    b.i = __builtin_amdgcn_update_dpp(0, a.i, 0x112, 0xf, 0xf, false); a.f += b.f; // row_shr:2
    b.i = __builtin_amdgcn_update_dpp(0, a.i, 0x111, 0xf, 0xf, false); a.f += b.f; // row_shr:1
    return a.f;
}

// ---------------------------------------------------------------------------
// Weight prep (1 block). Pair-packed layouts for the f2 (v_pk_f32) d-loop:
//   pwa4[j] = {wx[2j],wx[2j+1], wy[2j],wy[2j+1]}   (wx/wy/wz scaled by 2log2e)
//   pwb4[j] = {wz[2j],wz[2j+1], wv[2j],wv[2j+1]}   (wv = w2, unscaled)
//   gxy4[j] = {Gx[2j],Gx[2j+1], Gy[2j],Gy[2j+1]}   (G = 4*w2*W1, f32 — R17)
//   gz2[j]  = {Gz[2j],Gz[2j+1]}
// identities: ex = e^{2p} = exp2(x·pw); r = 1/(1+ex); t = 1-2r;
//             e = sumw2 - 2 sum w2 r; (1-t^2)/4 = r - r^2.
// ---------------------------------------------------------------------------
__global__ void prep_kernel(const float* __restrict__ W1, const float* __restrict__ w2,
                            float4* __restrict__ pwa4, float4* __restrict__ pwb4,
                            float4* __restrict__ gxy4, float2* __restrict__ gz2,
                            float* __restrict__ sumw2)
{
    __shared__ float spx[HID], spy[HID], spz[HID], spv[HID];
    __shared__ float sgx[HID], sgy[HID], sgz[HID];
    __shared__ float sw_[2];
    const float L2E2 = 2.885390082f;     // 2*log2(e)
    int d = threadIdx.x;                 // 128 threads
    float w0 = W1[d], w1 = W1[HID + d], wc = W1[2 * HID + d], wv = w2[d];
    spx[d] = L2E2 * w0; spy[d] = L2E2 * w1; spz[d] = L2E2 * wc; spv[d] = wv;
    sgx[d] = 4.f * wv * w0; sgy[d] = 4.f * wv * w1; sgz[d] = 4.f * wv * wc;
    float v = wv;
    for (int off = 32; off; off >>= 1) v += __shfl_down(v, off, 64);
    if ((d & 63) == 0) sw_[d >> 6] = v;
    __syncthreads();
    if (d == 0) sumw2[0] = sw_[0] + sw_[1];
    if (d < HID / 2) {
        int b = 2 * d;
        pwa4[d] = make_float4(spx[b], spx[b + 1], spy[b], spy[b + 1]);
        pwb4[d] = make_float4(spz[b], spz[b + 1], spv[b], spv[b + 1]);
        gxy4[d] = make_float4(sgx[b], sgx[b + 1], sgy[b], sgy[b + 1]);
        gz2[d]  = make_float2(sgz[b], sgz[b + 1]);
    }
}

// ---------------------------------------------------------------------------
// Edge MLP with block-local compaction: block owns 32 atoms (2048 edges).
// Phase A compacts unmasked local ids into LDS and stores the per-64-edge
// unmask BITMAP (no gr8 zero-fill — all gr8 reads downstream are bm-gated).
// Phase B: dense d-loop. R17: (1) G-accumulation in packed f32 (6 pk_fma
// per 4 dims, replacing cvt_pkrtz+fdot2 — fewer ops, better precision);
// (2) g2 stash as ushort (LDS 21->16.6KB => 8 blocks/CU); (3) software-
// pipelined x/list prefetch hides the 12B load under the d-loop.
// Phase C: block reduces its own 32 atoms' FIRST-term sums -> first[n].
// ---------------------------------------------------------------------------
__global__ __launch_bounds__(256) void edge_local(
    const float* __restrict__ x, const int* __restrict__ mask,
    const int* __restrict__ batch,
    const float4* __restrict__ pwa4, const float4* __restrict__ pwb4,
    const float4* __restrict__ gxy4, const float2* __restrict__ gz2,
    const float* __restrict__ sumw2p,
    uint2* __restrict__ gr8, ull* __restrict__ bm, float* __restrict__ part,
    float* __restrict__ first)
{
    __shared__ unsigned short list[EDGES_PB];
    __shared__ uint   sgL[EDGES_PB];     // per-edge grad lo word (bf16 g0|g1)
    __shared__ ushort sgH[EDGES_PB];     // per-edge grad g2 (bf16 bits)
    __shared__ int   lcnt;
    __shared__ float sp[N_STRUCT];
    __shared__ int   sbatch[ATOMS_PB];

    const int tid = threadIdx.x, lane = tid & 63;
    const int ebase = blockIdx.x * EDGES_PB;

    if (tid == 0) lcnt = 0;
    if (tid < N_STRUCT) sp[tid] = 0.f;
    if (tid < ATOMS_PB) sbatch[tid] = batch[blockIdx.x * ATOMS_PB + tid];
    __syncthreads();

    #pragma unroll
    for (int p = 0; p < EDGES_PB / 256; ++p) {           // 8 passes, coalesced
        int le = p * 256 + tid;
        int m = mask[ebase + le];
        unsigned long long bal = __ballot(m == 0);
        int wcnt = __popcll(bal);
        int pre  = __popcll(bal & ((1ull << lane) - 1ull));
        int wbase;
        if (lane == 0) {
            wbase = atomicAdd(&lcnt, wcnt);              // block-local ticket
            bm[(ebase + le) >> 6] = bal;                 // unmask bitmap word
        }
        wbase = __shfl(wbase, 0, 64);
        if (m == 0) list[wbase + pre] = (unsigned short)le;
        else        { sgL[le] = 0u; sgH[le] = 0; }       // masked grad == 0 (LDS only)
    }
    __syncthreads();

    const int L = lcnt;
    const float sumw2 = sumw2p[0];

    // software-pipelined edge loop: prefetch next (list, x) during d-loop
    int   le_c = 0;
    float xc0 = 0.f, xc1 = 0.f, xc2 = 0.f;
    if (tid < L) {
        le_c = list[tid];
        const float* xp = x + (size_t)(ebase + le_c) * 3;
        xc0 = xp[0]; xc1 = xp[1]; xc2 = xp[2];
    }
    for (int i = tid; i < L; i += 256) {
        int   le_n = 0;
        float xn0 = 0.f, xn1 = 0.f, xn2 = 0.f;
        int inext = i + 256;
        if (inext < L) {
            le_n = list[inext];
            const float* xp = x + (size_t)(ebase + le_n) * 3;
            xn0 = xp[0]; xn1 = xp[1]; xn2 = xp[2];
        }

        int le  = le_c;
        int eid = ebase + le;
        const f2 x0v = {xc0, xc0}, x1v = {xc1, xc1}, x2v = {xc2, xc2};
        const f2 onev = {1.f, 1.f};
        f2 rs  = {0.f, 0.f};
        f2 g0v = {0.f, 0.f}, g1v = {0.f, 0.f}, g2v = {0.f, 0.f};
        for (int j = 0; j < HID / 2; j += 2) {           // 2 dim-pairs = 4 dims
            float4 Aa = pwa4[j],     Ab = pwb4[j];
            float4 Ba = pwa4[j + 1], Bb = pwb4[j + 1];
            float4 GXY0 = gxy4[j],   GXY1 = gxy4[j + 1];
            float2 GZ0  = gz2[j],    GZ1  = gz2[j + 1];
            f2 wx01 = {Aa.x, Aa.y}, wy01 = {Aa.z, Aa.w};
            f2 wz01 = {Ab.x, Ab.y}, wv01 = {Ab.z, Ab.w};
            f2 wx23 = {Ba.x, Ba.y}, wy23 = {Ba.z, Ba.w};
            f2 wz23 = {Bb.x, Bb.y}, wv23 = {Bb.z, Bb.w};
            f2 Gx0 = {GXY0.x, GXY0.y}, Gy0 = {GXY0.z, GXY0.w};
            f2 Gx1 = {GXY1.x, GXY1.y}, Gy1 = {GXY1.z, GXY1.w};
            f2 Gz0 = {GZ0.x, GZ0.y},   Gz1 = {GZ1.x, GZ1.y};
            f2 p01 = PKFMA(x0v, wx01, PKFMA(x1v, wy01, x2v * wz01));
            f2 p23 = PKFMA(x0v, wx23, PKFMA(x1v, wy23, x2v * wz23));
            f2 e01 = {EXP2(p01.x), EXP2(p01.y)};
            f2 e23 = {EXP2(p23.x), EXP2(p23.y)};
            f2 a01 = e01 + onev, a23 = e23 + onev;
            float pab = a01.x * a01.y, pcd = a23.x * a23.y;
            float q   = __builtin_amdgcn_rcpf(pab * pcd); // one rcp per 4 d
            float qab = q * pcd, qcd = q * pab;
            f2 r01 = (f2){qab, qab} * SWAP2(a01);         // {qab*ab, qab*aa}
            f2 r23 = (f2){qcd, qcd} * SWAP2(a23);
            rs = PKFMA(wv01, r01, rs);
            rs = PKFMA(wv23, r23, rs);
            f2 s01 = PKFMA(-r01, r01, r01);               // r-r^2 = (1-t^2)/4
            f2 s23 = PKFMA(-r23, r23, r23);
            g0v = PKFMA(s01, Gx0, g0v);                   // packed f32 G-dot
            g1v = PKFMA(s01, Gy0, g1v);
            g2v = PKFMA(s01, Gz0, g2v);
            g0v = PKFMA(s23, Gx1, g0v);
            g1v = PKFMA(s23, Gy1, g1v);
            g2v = PKFMA(s23, Gz1, g2v);
        }
        float e = fmaf(-2.f, rs.x + rs.y, sumw2);
        uint lo = bf_rne(g0v.x + g0v.y) | (bf_rne(g1v.x + g1v.y) << 16);
        uint hi = bf_rne(g2v.x + g2v.y);
        gr8[eid] = make_uint2(lo, hi);
        sgL[le] = lo; sgH[le] = (ushort)hi;               // LDS stash for phase C
        atomicAdd(&sp[sbatch[le >> 6]], e);

        le_c = le_n; xc0 = xn0; xc1 = xn1; xc2 = xn2;
    }
    __syncthreads();
    if (tid < N_STRUCT) part[(size_t)tid * NBLK_EL + blockIdx.x] = sp[tid];

    // phase C: FIRST-term per-atom sums. 16 threads/atom, 2 passes.
    #pragma unroll
    for (int pass = 0; pass < 2; ++pass) {
        int la = pass * 16 + (tid >> 4);                 // atom 0..31
        int o  = tid & 15;
        float f0 = 0.f, f1 = 0.f, f2_ = 0.f;
        #pragma unroll
        for (int j = 0; j < 4; ++j) {                    // edges k = o*4+j
            int le = la * 64 + o * 4 + j;
            uint lo = sgL[le];
            f0  += ubf_lo(lo);
            f1  += ubf_hi(lo);
            f2_ += __uint_as_float((uint)sgH[le] << 16);
        }
        f0 = red16(f0); f1 = red16(f1); f2_ = red16(f2_);
        if (o == 15) {
            float* fo = first + (size_t)(blockIdx.x * ATOMS_PB + la) * 3;
            fo[0] = f0; fo[1] = f1; fo[2] = f2_;
        }
    }
}

// ---------------------------------------------------------------------------
// Forces (gather-only). R15 structure EXACTLY (branchless clamped loads,
// 8 waves/SIMD, normal cached loads — R16's nontemporal regressed 39µs and
// is reverted). FROZEN: 6 experiments establish ~155µs as the latency-
// structural floor for 4.8M random accesses at ~16 outstanding misses/CU.
// Blocks 0..31 also reduce preds partials.
// ---------------------------------------------------------------------------
__global__ __launch_bounds__(256, 8) void atom_fused(
    const uint2* __restrict__ gr8, const int* __restrict__ nidx,
    const int* __restrict__ pos,
    const ull* __restrict__ bm, const float* __restrict__ part,
    const float* __restrict__ first,
    float* __restrict__ out)
{
    __shared__ int tile[64][33];
    __shared__ float sv[4];
    const int tid = threadIdx.x, lane = tid & 63, w = tid >> 6;
    const int n0 = blockIdx.x * 32;

    #pragma unroll
    for (int i = 0; i < 8; ++i) {                  // coalesced read of nidx[K,N]
        int k = i * 8 + (tid >> 5), c = tid & 31;
        tile[k][c] = nidx[k * N_ATOMS + n0 + c];
    }
    __syncthreads();

    const int grp = lane >> 4, kk = lane & 15;

    #pragma unroll
    for (int s = 0; s < 2; ++s) {                  // wave owns 8 atoms: 2 batches of 4
        int nl = w * 8 + s * 4 + grp;
        int n  = n0 + nl;
        ull bmw = bm[n];                           // per-atom unmask word

        // phase 1: dense pos loads + clamped reverse-ids (no branches)
        int  gs[4];
        uint sb[4];
        #pragma unroll
        for (int ks = 0; ks < 4; ++ks) {
            int k  = ks * 16 + kk;
            int ei = n * 64 + k;
            sb[ks] = (uint)((bmw >> k) & 1ull);    // source edge unmasked?
            int p  = pos[ei];                      // unconditional, coalesced
            int gt = tile[k][nl] * 64 + p;
            gs[ks] = sb[ks] ? gt : 0;              // clamp dead lanes to word 0
        }

        // phase 2: 4 unconditional filter-word loads (random 8B, L2; dead->bm[0])
        ull fw[4];
        #pragma unroll
        for (int ks = 0; ks < 4; ++ks)
            fw[ks] = bm[gs[ks] >> 6];

        // phase 3: 4 unconditional gathers (failed lanes clamp to line 0, L1)
        uint ok[4];
        int  ga[4];
        #pragma unroll
        for (int ks = 0; ks < 4; ++ks) {
            ok[ks] = sb[ks] & (uint)((fw[ks] >> (gs[ks] & 63)) & 1ull);
            ga[ks] = ok[ks] ? gs[ks] : 0;
        }
        float f0 = 0.f, f1 = 0.f, f2_ = 0.f;
        #pragma unroll
        for (int ks = 0; ks < 4; ++ks) {
            uint2 B = gr8[ga[ks]];
            uint bx = ok[ks] ? B.x : 0u;
            uint by = ok[ks] ? B.y : 0u;
            f0  += ubf_lo(bx);
            f1  += ubf_hi(bx);
            f2_ += ubf_lo(by);
        }

        // phase 4: reduce SECOND term, store first - second
        f0 = red16(f0); f1 = red16(f1); f2_ = red16(f2_);
        if (kk == 15) {
            const float* fi = first + (size_t)n * 3;
            float* fo = out + N_STRUCT + (size_t)n * 3;
            fo[0] = fi[0] - f0; fo[1] = fi[1] - f1; fo[2] = fi[2] - f2_;
        }
    }

    if (blockIdx.x < N_STRUCT) {                   // fused preds reduction
        int s = blockIdx.x;
        float v = 0.f;
        for (int i = tid; i < NBLK_EL; i += 256) v += part[(size_t)s * NBLK_EL + i];
        for (int off = 32; off; off >>= 1) v += __shfl_down(v, off, 64);
        if (lane == 0) sv[w] = v;
        __syncthreads();
        if (tid == 0) out[s] = sv[0] + sv[1] + sv[2] + sv[3];
    }
}

// ---------------------------------------------------------------------------
extern "C" void kernel_launch(void* const* d_in, const int* in_sizes, int n_in,
                              void* d_out, int out_size, void* d_ws, size_t ws_size,
                              hipStream_t stream)
{
    const float* x    = (const float*)d_in[0];
    const int*   nidx = (const int*)d_in[1];   // [K, N]
    const int*   npos = (const int*)d_in[2];   // [N, K]
    const int*   mask = (const int*)d_in[3];   // [N, K]
    const int*   bidx = (const int*)d_in[4];   // [N]
    const float* W1   = (const float*)d_in[5]; // [3, HID]
    const float* w2   = (const float*)d_in[6]; // [HID]
    float* out = (float*)d_out;

    char* ws = (char*)d_ws;
    uint2* gr8  = (uint2*)ws;                                       // 51.2 MB
    ull*   bm   = (ull*)(ws + (size_t)N_EDGE * 8);                  // 800 KB
    float* part = (float*)(ws + (size_t)N_EDGE * 8 + (size_t)(N_EDGE / 64) * 8);
    char*  t1   = ws + (size_t)N_EDGE * 8 + (size_t)(N_EDGE / 64) * 8
                     + (size_t)N_STRUCT * NBLK_EL * sizeof(float);
    float* first = (float*)t1;                                      // 1.2 MB
    char*  tail  = t1 + (size_t)N_ATOMS * 3 * sizeof(float);
    float4* pwa4  = (float4*)tail;                                  // 1 KB
    float4* pwb4  = (float4*)(tail + 1024);                         // 1 KB
    float4* gxy4  = (float4*)(tail + 2048);                         // 1 KB
    float2* gz2   = (float2*)(tail + 3072);                         // 512 B
    float*  sumw2 = (float*)(tail + 3584);

    hipLaunchKernelGGL(prep_kernel, dim3(1), dim3(128), 0, stream,
                       W1, w2, pwa4, pwb4, gxy4, gz2, sumw2);
    hipLaunchKernelGGL(edge_local, dim3(NBLK_EL), dim3(256), 0, stream,
                       x, mask, bidx, pwa4, pwb4, gxy4, gz2, sumw2, gr8, bm, part, first);
    hipLaunchKernelGGL(atom_fused, dim3(NBLK_A), dim3(256), 0, stream,
                       gr8, nidx, npos, bm, part, first, out);
}